// Round 2
// baseline (334.651 us; speedup 1.0000x reference)
//
#include <hip/hip_runtime.h>
#include <math.h>

#define DDIM 4096
#define NSEG 100
#define HDIM 128
#define BROWS 4096
#define TOPK 10

__device__ __forceinline__ float gelu_f(float x) {
    return 0.5f * x * (1.0f + erff(x * 0.70710678118654752440f));
}

// ---------- K1: seg-side GEMM: segp[ks][n][col] partials of seg @ [iw1 | rw1_lo] ----------
// grid (25 n-groups of 4, 16 k-slices of 256), block 256 (col 0..255)
__global__ void k_seg_gemm(const float* __restrict__ seg,
                           const float* __restrict__ iw1,
                           const float* __restrict__ rw1,
                           float* __restrict__ segp) {
    __shared__ float segT[256][4];   // [k][n] — float4 row per k
    int ng = blockIdx.x;             // n = ng*4 + j
    int ks = blockIdx.y * 256;
    int tid = threadIdx.x;
    #pragma unroll
    for (int j = 0; j < 4; ++j)
        segT[tid][j] = seg[(size_t)(ng * 4 + j) * DDIM + ks + tid];
    __syncthreads();

    int col = tid;
    float a0 = 0.f, a1 = 0.f, a2 = 0.f, a3 = 0.f;
    const float* w = (col < HDIM) ? (iw1 + col)
                                  : (rw1 + (size_t)DDIM * HDIM + (col - HDIM));
    for (int k = 0; k < 256; ++k) {
        float wv = w[(size_t)(ks + k) * HDIM];
        float4 s4 = *reinterpret_cast<const float4*>(&segT[k][0]);
        a0 += s4.x * wv; a1 += s4.y * wv; a2 += s4.z * wv; a3 += s4.w * wv;
    }
    float* outp = segp + (size_t)blockIdx.y * (NSEG * 256) + (size_t)(ng * 4) * 256 + col;
    outp[0] = a0; outp[256] = a1; outp[512] = a2; outp[768] = a3;
}

// ---------- K2: reduce k-slices -> importance, score-coeff, shw(+rb1) ----------
// grid 100, block 256
__global__ void k_seg_red(const float* __restrict__ segp,
                          const int* __restrict__ positions,
                          const float* __restrict__ ib1,
                          const float* __restrict__ iw2,
                          const float* __restrict__ ib2,
                          const float* __restrict__ rb1,
                          float* __restrict__ shw, float* __restrict__ impA,
                          float* __restrict__ cA) {
    __shared__ float red[HDIM];
    int n = blockIdx.x, tid = threadIdx.x;
    float v = 0.f;
    #pragma unroll
    for (int s = 0; s < 16; ++s)
        v += segp[(size_t)s * (NSEG * 256) + (size_t)n * 256 + tid];
    if (tid < HDIM) {
        red[tid] = gelu_f(v + ib1[tid]) * iw2[tid];
    } else {
        shw[(size_t)n * HDIM + (tid - HDIM)] = v + rb1[tid - HDIM];  // rb1 pre-added
    }
    __syncthreads();
    if (tid == 0) {
        float s = 0.f;
        for (int j = 0; j < HDIM; ++j) s += red[j];
        float imp = 1.f / (1.f + expf(-(s + ib2[0])));
        float pf = powf(0.95f, (float)NSEG - (float)positions[n] - 1.0f);
        impA[n] = imp;
        cA[n] = imp * (0.5f + 0.5f * pf);
    }
}

// ---------- K3: qh = query @ rw1[:D], fp32 SGEMM, M-tile 32 x N 128, k-split 8 ----------
// grid (128, 8), block 256: tx=tid&31 (4 cols each), ty=tid>>5 (4 rows each)
__global__ void k_qh(const float* __restrict__ query,
                     const float* __restrict__ rw1,
                     float* __restrict__ qhp) {
    __shared__ float As[32][36];     // [k][m], padded stride 36 (16B-aligned rows)
    __shared__ float Bs[32][HDIM];   // [k][n]
    int tid = threadIdx.x;
    int tx = tid & 31, ty = tid >> 5;
    int m0 = blockIdx.x * 32;
    int ks = blockIdx.y * 512;
    float acc[4][4] = {{0.f}};

    for (int c = 0; c < 16; ++c) {
        int kc = ks + c * 32;
        // stage A (32m x 32k), transposed into As[k][m]
        float4 a4 = *reinterpret_cast<const float4*>(
            query + (size_t)(m0 + (tid >> 3)) * DDIM + kc + (tid & 7) * 4);
        int kb = (tid & 7) * 4, mm = tid >> 3;
        As[kb + 0][mm] = a4.x; As[kb + 1][mm] = a4.y;
        As[kb + 2][mm] = a4.z; As[kb + 3][mm] = a4.w;
        // stage B (32k x 128n) direct
        #pragma unroll
        for (int r = 0; r < 4; ++r) {
            int kr = ty + r * 8;
            *reinterpret_cast<float4*>(&Bs[kr][tx * 4]) =
                *reinterpret_cast<const float4*>(rw1 + (size_t)(kc + kr) * HDIM + tx * 4);
        }
        __syncthreads();
        #pragma unroll
        for (int kk = 0; kk < 32; ++kk) {
            float4 av = *reinterpret_cast<const float4*>(&As[kk][ty * 4]);
            float4 bv = *reinterpret_cast<const float4*>(&Bs[kk][tx * 4]);
            acc[0][0] += av.x * bv.x; acc[0][1] += av.x * bv.y; acc[0][2] += av.x * bv.z; acc[0][3] += av.x * bv.w;
            acc[1][0] += av.y * bv.x; acc[1][1] += av.y * bv.y; acc[1][2] += av.y * bv.z; acc[1][3] += av.y * bv.w;
            acc[2][0] += av.z * bv.x; acc[2][1] += av.z * bv.y; acc[2][2] += av.z * bv.z; acc[2][3] += av.z * bv.w;
            acc[3][0] += av.w * bv.x; acc[3][1] += av.w * bv.y; acc[3][2] += av.w * bv.z; acc[3][3] += av.w * bv.w;
        }
        __syncthreads();
    }
    float* outp = qhp + (size_t)blockIdx.y * (BROWS * HDIM);
    #pragma unroll
    for (int i = 0; i < 4; ++i) {
        int row = m0 + ty * 4 + i;
        float4 o = make_float4(acc[i][0], acc[i][1], acc[i][2], acc[i][3]);
        *reinterpret_cast<float4*>(&outp[(size_t)row * HDIM + tx * 4]) = o;
    }
}

// ---------- K4: per-row rel + top-10 + weights + context + out ----------
// grid 4096, block 256
__global__ void k_ctx(const float* __restrict__ query,
                      const float* __restrict__ seg,
                      const float* __restrict__ rw2,
                      const float* __restrict__ rb2,
                      const float* __restrict__ qhp,
                      const float* __restrict__ shw,
                      const float* __restrict__ impA,
                      const float* __restrict__ cA,
                      float* __restrict__ out) {
    __shared__ float qs[HDIM], rw2s[HDIM], scores[128], wimp[128];
    __shared__ float wv[TOPK];
    __shared__ int idxw[TOPK];
    int b = blockIdx.x, tid = threadIdx.x;

    // Phase 1: sum k-split partials of qh
    if (tid < HDIM) {
        size_t o = (size_t)b * HDIM + tid;
        float v = 0.f;
        #pragma unroll
        for (int s = 0; s < 8; ++s) v += qhp[(size_t)s * (BROWS * HDIM) + o];
        qs[tid] = v;
        rw2s[tid] = rw2[tid];
    }
    __syncthreads();

    // Phase 2: rel + scores, one wave per segment round-robin
    int wave = tid >> 6, lane = tid & 63;
    float rb2f = rb2[0];
    for (int n = wave; n < NSEG; n += 4) {
        const float* sh_n = shw + (size_t)n * HDIM;
        float t = gelu_f(qs[lane] + sh_n[lane]) * rw2s[lane]
                + gelu_f(qs[lane + 64] + sh_n[lane + 64]) * rw2s[lane + 64];
        #pragma unroll
        for (int off = 32; off > 0; off >>= 1) t += __shfl_down(t, off);
        if (lane == 0) {
            float rel = 1.f / (1.f + expf(-(t + rb2f)));
            scores[n] = cA[n] * rel;
            wimp[n]   = impA[n] * rel;
        }
    }
    __syncthreads();

    // Phase 3: iterative top-10 by wave 0; tie-break lower index (matches lax.top_k)
    if (tid < 64) {
        float s1 = scores[lane];
        int i2 = lane + 64;
        float s2 = (i2 < NSEG) ? scores[i2] : -1e30f;
        float wsum = 0.f;
        for (int k = 0; k < TOPK; ++k) {
            float s; int i;
            if (s2 > s1) { s = s2; i = i2; } else { s = s1; i = lane; }
            #pragma unroll
            for (int off = 1; off < 64; off <<= 1) {
                float os = __shfl_xor(s, off);
                int oi = __shfl_xor(i, off);
                if (os > s || (os == s && oi < i)) { s = os; i = oi; }
            }
            if (lane == 0) {
                idxw[k] = i;
                float ww = wimp[i];
                wv[k] = ww;
                wsum += ww;
            }
            if (i == lane) s1 = -1e30f;
            if (i == i2)   s2 = -1e30f;
        }
        if (lane == 0) {
            float denom = wsum + 1e-8f;
            for (int k = 0; k < TOPK; ++k) wv[k] = wv[k] / denom;
        }
    }
    __syncthreads();

    // Phase 4: out = query + sum_k w_k * seg[idx_k], float4 vectorized
    float w[TOPK];
    const float* srow[TOPK];
    #pragma unroll
    for (int k = 0; k < TOPK; ++k) { w[k] = wv[k]; srow[k] = seg + (size_t)idxw[k] * DDIM; }
    const float* qrow = query + (size_t)b * DDIM;
    float* orow = out + (size_t)b * DDIM;
    #pragma unroll
    for (int it = 0; it < 4; ++it) {
        int d0 = it * 1024 + tid * 4;
        float4 q4 = *reinterpret_cast<const float4*>(qrow + d0);
        #pragma unroll
        for (int k = 0; k < TOPK; ++k) {
            float4 s4 = *reinterpret_cast<const float4*>(srow[k] + d0);
            q4.x += w[k] * s4.x; q4.y += w[k] * s4.y;
            q4.z += w[k] * s4.z; q4.w += w[k] * s4.w;
        }
        *reinterpret_cast<float4*>(orow + d0) = q4;
    }
}

extern "C" void kernel_launch(void* const* d_in, const int* in_sizes, int n_in,
                              void* d_out, int out_size, void* d_ws, size_t ws_size,
                              hipStream_t stream) {
    const float* query = (const float*)d_in[0];
    const float* seg   = (const float*)d_in[1];
    const int*   pos   = (const int*)d_in[2];
    const float* iw1   = (const float*)d_in[3];
    const float* ib1   = (const float*)d_in[4];
    const float* iw2   = (const float*)d_in[5];
    const float* ib2   = (const float*)d_in[6];
    const float* rw1   = (const float*)d_in[7];
    const float* rb1   = (const float*)d_in[8];
    const float* rw2   = (const float*)d_in[9];
    const float* rb2   = (const float*)d_in[10];
    float* out = (float*)d_out;

    char* ws = (char*)d_ws;
    float* qhp  = (float*)(ws);                                   // 8*4096*128*4 = 16 MB
    float* segp = (float*)(ws + 16 * 1024 * 1024);                // 16*100*256*4 = 1.6 MB
    float* shw  = (float*)(ws + 18 * 1024 * 1024);                // 100*128*4
    float* impA = (float*)(ws + 18 * 1024 * 1024 + 51200);
    float* cA   = (float*)(ws + 18 * 1024 * 1024 + 51200 + 512);

    hipLaunchKernelGGL(k_seg_gemm, dim3(25, 16), dim3(256), 0, stream, seg, iw1, rw1, segp);
    hipLaunchKernelGGL(k_seg_red, dim3(NSEG), dim3(256), 0, stream,
                       segp, pos, ib1, iw2, ib2, rb1, shw, impA, cA);
    hipLaunchKernelGGL(k_qh, dim3(128, 8), dim3(256), 0, stream, query, rw1, qhp);
    hipLaunchKernelGGL(k_ctx, dim3(BROWS), dim3(256), 0, stream,
                       query, seg, rw2, rb2, qhp, shw, impA, cA, out);
}

// Round 3
// 307.886 us; speedup vs baseline: 1.0869x; 1.0869x over previous
//
#include <hip/hip_runtime.h>
#include <math.h>

#define DDIM 4096
#define NSEG 100
#define HDIM 128
#define BROWS 4096
#define TOPK 10

// Branch-free gelu: A&S 7.1.26 erf (abs err <= 1.5e-7), v_exp_f32 + v_rcp_f32.
__device__ __forceinline__ float gelu_f(float x) {
    float u  = x * 0.70710678118654752440f;
    float au = fminf(fabsf(u), 3.9f);                 // erf(3.9) == 1 to fp32
    float t  = __builtin_amdgcn_rcpf(fmaf(0.3275911f, au, 1.0f));
    float p  = fmaf(fmaf(fmaf(fmaf(1.061405429f, t, -1.453152027f), t,
                              1.421413741f), t, -0.284496736f), t, 0.254829592f) * t;
    float e  = __expf(-au * au);
    float er = fmaf(-p, e, 1.0f);                     // erf(|u|)
    er = copysignf(er, u);
    return 0.5f * x * (1.0f + er);
}

// ---------- K1: seg-side GEMM partials: segp[ks][n][col], 64 k-slices of 64 ----------
// grid (25, 64), block 256
__global__ void k_seg_gemm(const float* __restrict__ seg,
                           const float* __restrict__ iw1,
                           const float* __restrict__ rw1,
                           float* __restrict__ segp) {
    __shared__ float segT[64][5];    // [k][n], pad -> 2-way max on write
    int ng = blockIdx.x;
    int ks = blockIdx.y * 64;
    int tid = threadIdx.x;
    {
        int k = tid & 63, j = tid >> 6;
        segT[k][j] = seg[(size_t)(ng * 4 + j) * DDIM + ks + k];
    }
    __syncthreads();

    int col = tid;
    float a0 = 0.f, a1 = 0.f, a2 = 0.f, a3 = 0.f;
    const float* w = (col < HDIM) ? (iw1 + col)
                                  : (rw1 + (size_t)DDIM * HDIM + (col - HDIM));
    #pragma unroll 8
    for (int k = 0; k < 64; ++k) {
        float wv = w[(size_t)(ks + k) * HDIM];
        a0 = fmaf(segT[k][0], wv, a0);
        a1 = fmaf(segT[k][1], wv, a1);
        a2 = fmaf(segT[k][2], wv, a2);
        a3 = fmaf(segT[k][3], wv, a3);
    }
    float* outp = segp + (size_t)blockIdx.y * (NSEG * 256) + (size_t)(ng * 4) * 256 + col;
    outp[0] = a0; outp[256] = a1; outp[512] = a2; outp[768] = a3;
}

// ---------- K2: reduce 64 k-slices -> importance, coeff, shw(+rb1) ----------
// grid 100, block 256
__global__ void k_seg_red(const float* __restrict__ segp,
                          const int* __restrict__ positions,
                          const float* __restrict__ ib1,
                          const float* __restrict__ iw2,
                          const float* __restrict__ ib2,
                          const float* __restrict__ rb1,
                          float* __restrict__ shw, float* __restrict__ impA,
                          float* __restrict__ cA) {
    __shared__ float red[HDIM];
    int n = blockIdx.x, tid = threadIdx.x;
    float v = 0.f;
    #pragma unroll
    for (int s = 0; s < 64; ++s)
        v += segp[(size_t)s * (NSEG * 256) + (size_t)n * 256 + tid];
    if (tid < HDIM) {
        red[tid] = gelu_f(v + ib1[tid]) * iw2[tid];
    } else {
        shw[(size_t)n * HDIM + (tid - HDIM)] = v + rb1[tid - HDIM];
    }
    __syncthreads();
    if (tid == 0) {
        float s = 0.f;
        for (int j = 0; j < HDIM; ++j) s += red[j];
        float imp = 1.f / (1.f + expf(-(s + ib2[0])));
        float pf = powf(0.95f, (float)NSEG - (float)positions[n] - 1.0f);
        impA[n] = imp;
        cA[n] = imp * (0.5f + 0.5f * pf);
    }
}

// ---------- K3: qh partials, fp32, 64m x 128n tile, 8x4 acc/thread ----------
// grid (64, 8), block 256. 32 chunks of 16 k, register-prefetch pipelined.
__global__ void k_qh(const float* __restrict__ query,
                     const float* __restrict__ rw1,
                     float* __restrict__ qhp) {
    __shared__ float As[16][68];     // [k][m], pad 68 -> 2-way max on transposed write
    __shared__ float Bs[16][HDIM];   // [k][n]
    int tid = threadIdx.x;
    int tx = tid & 31;               // n0 = tx*4
    int ty = tid >> 5;               // m0 = ty*8
    int m0g = blockIdx.x * 64;
    int ksg = blockIdx.y * 512;

    float acc[8][4];
    #pragma unroll
    for (int i = 0; i < 8; ++i)
        #pragma unroll
        for (int j = 0; j < 4; ++j) acc[i][j] = 0.f;

    // A stage map: row ar = tid>>2 (0..63), k-quad ak = (tid&3)*4
    int ar = tid >> 2, ak = (tid & 3) * 4;
    // B stage map: row bk = tid>>4 (0..15), col bn = (tid&15)*8
    int bk = tid >> 4, bn = (tid & 15) * 8;

    const float* aptr = query + (size_t)(m0g + ar) * DDIM + ksg + ak;
    const float* bptr = rw1 + (size_t)(ksg + bk) * HDIM + bn;

    float4 areg = *reinterpret_cast<const float4*>(aptr);
    float4 breg0 = *reinterpret_cast<const float4*>(bptr);
    float4 breg1 = *reinterpret_cast<const float4*>(bptr + 4);

    for (int c = 0; c < 32; ++c) {
        __syncthreads();
        As[ak + 0][ar] = areg.x; As[ak + 1][ar] = areg.y;
        As[ak + 2][ar] = areg.z; As[ak + 3][ar] = areg.w;
        *reinterpret_cast<float4*>(&Bs[bk][bn]) = breg0;
        *reinterpret_cast<float4*>(&Bs[bk][bn + 4]) = breg1;
        __syncthreads();
        if (c < 31) {
            const float* ap = aptr + (c + 1) * 16;
            const float* bp = bptr + (size_t)(c + 1) * 16 * HDIM;
            areg = *reinterpret_cast<const float4*>(ap);
            breg0 = *reinterpret_cast<const float4*>(bp);
            breg1 = *reinterpret_cast<const float4*>(bp + 4);
        }
        #pragma unroll
        for (int kk = 0; kk < 16; ++kk) {
            float4 a0 = *reinterpret_cast<const float4*>(&As[kk][ty * 8]);
            float4 a1 = *reinterpret_cast<const float4*>(&As[kk][ty * 8 + 4]);
            float4 b  = *reinterpret_cast<const float4*>(&Bs[kk][tx * 4]);
            float am[8] = {a0.x, a0.y, a0.z, a0.w, a1.x, a1.y, a1.z, a1.w};
            #pragma unroll
            for (int i = 0; i < 8; ++i) {
                acc[i][0] = fmaf(am[i], b.x, acc[i][0]);
                acc[i][1] = fmaf(am[i], b.y, acc[i][1]);
                acc[i][2] = fmaf(am[i], b.z, acc[i][2]);
                acc[i][3] = fmaf(am[i], b.w, acc[i][3]);
            }
        }
    }
    float* outp = qhp + (size_t)blockIdx.y * (BROWS * HDIM);
    #pragma unroll
    for (int i = 0; i < 8; ++i) {
        int row = m0g + ty * 8 + i;
        float4 o = make_float4(acc[i][0], acc[i][1], acc[i][2], acc[i][3]);
        *reinterpret_cast<float4*>(&outp[(size_t)row * HDIM + tx * 4]) = o;
    }
}

// ---------- K4: per-row rel + top-10 + weights + context + out ----------
// grid 4096, block 256
__global__ void k_ctx(const float* __restrict__ query,
                      const float* __restrict__ seg,
                      const float* __restrict__ rw2,
                      const float* __restrict__ rb2,
                      const float* __restrict__ qhp,
                      const float* __restrict__ shw,
                      const float* __restrict__ impA,
                      const float* __restrict__ cA,
                      float* __restrict__ out) {
    __shared__ float qs[HDIM], rw2s[HDIM], scores[128], wimp[128];
    __shared__ float wv[TOPK];
    __shared__ int idxw[TOPK];
    int b = blockIdx.x, tid = threadIdx.x;

    if (tid < HDIM) {
        size_t o = (size_t)b * HDIM + tid;
        float v = 0.f;
        #pragma unroll
        for (int s = 0; s < 8; ++s) v += qhp[(size_t)s * (BROWS * HDIM) + o];
        qs[tid] = v;
        rw2s[tid] = rw2[tid];
    }
    __syncthreads();

    int wave = tid >> 6, lane = tid & 63;
    float rb2f = rb2[0];
    for (int n = wave; n < NSEG; n += 4) {
        const float* sh_n = shw + (size_t)n * HDIM;
        float t = gelu_f(qs[lane] + sh_n[lane]) * rw2s[lane]
                + gelu_f(qs[lane + 64] + sh_n[lane + 64]) * rw2s[lane + 64];
        #pragma unroll
        for (int off = 32; off > 0; off >>= 1) t += __shfl_down(t, off);
        if (lane == 0) {
            float rel = 1.f / (1.f + expf(-(t + rb2f)));
            scores[n] = cA[n] * rel;
            wimp[n]   = impA[n] * rel;
        }
    }
    __syncthreads();

    if (tid < 64) {
        float s1 = scores[lane];
        int i2 = lane + 64;
        float s2 = (i2 < NSEG) ? scores[i2] : -1e30f;
        float wsum = 0.f;
        for (int k = 0; k < TOPK; ++k) {
            float s; int i;
            if (s2 > s1) { s = s2; i = i2; } else { s = s1; i = lane; }
            #pragma unroll
            for (int off = 1; off < 64; off <<= 1) {
                float os = __shfl_xor(s, off);
                int oi = __shfl_xor(i, off);
                if (os > s || (os == s && oi < i)) { s = os; i = oi; }
            }
            if (lane == 0) {
                idxw[k] = i;
                float ww = wimp[i];
                wv[k] = ww;
                wsum += ww;
            }
            if (i == lane) s1 = -1e30f;
            if (i == i2)   s2 = -1e30f;
        }
        if (lane == 0) {
            float denom = wsum + 1e-8f;
            for (int k = 0; k < TOPK; ++k) wv[k] = wv[k] / denom;
        }
    }
    __syncthreads();

    float w[TOPK];
    const float* srow[TOPK];
    #pragma unroll
    for (int k = 0; k < TOPK; ++k) { w[k] = wv[k]; srow[k] = seg + (size_t)idxw[k] * DDIM; }
    const float* qrow = query + (size_t)b * DDIM;
    float* orow = out + (size_t)b * DDIM;
    #pragma unroll
    for (int it = 0; it < 4; ++it) {
        int d0 = it * 1024 + tid * 4;
        float4 q4 = *reinterpret_cast<const float4*>(qrow + d0);
        #pragma unroll
        for (int k = 0; k < TOPK; ++k) {
            float4 s4 = *reinterpret_cast<const float4*>(srow[k] + d0);
            q4.x = fmaf(w[k], s4.x, q4.x); q4.y = fmaf(w[k], s4.y, q4.y);
            q4.z = fmaf(w[k], s4.z, q4.z); q4.w = fmaf(w[k], s4.w, q4.w);
        }
        *reinterpret_cast<float4*>(orow + d0) = q4;
    }
}

extern "C" void kernel_launch(void* const* d_in, const int* in_sizes, int n_in,
                              void* d_out, int out_size, void* d_ws, size_t ws_size,
                              hipStream_t stream) {
    const float* query = (const float*)d_in[0];
    const float* seg   = (const float*)d_in[1];
    const int*   pos   = (const int*)d_in[2];
    const float* iw1   = (const float*)d_in[3];
    const float* ib1   = (const float*)d_in[4];
    const float* iw2   = (const float*)d_in[5];
    const float* ib2   = (const float*)d_in[6];
    const float* rw1   = (const float*)d_in[7];
    const float* rb1   = (const float*)d_in[8];
    const float* rw2   = (const float*)d_in[9];
    const float* rb2   = (const float*)d_in[10];
    float* out = (float*)d_out;

    char* ws = (char*)d_ws;
    float* qhp  = (float*)(ws);                                   // 8*4096*128*4 = 16.8 MB
    float* segp = (float*)(ws + 17 * 1024 * 1024);                // 64*100*256*4 = 6.55 MB
    float* shw  = (float*)(ws + 24 * 1024 * 1024);                // 100*128*4
    float* impA = (float*)(ws + 24 * 1024 * 1024 + 51200);
    float* cA   = (float*)(ws + 24 * 1024 * 1024 + 51200 + 512);

    hipLaunchKernelGGL(k_seg_gemm, dim3(25, 64), dim3(256), 0, stream, seg, iw1, rw1, segp);
    hipLaunchKernelGGL(k_seg_red, dim3(NSEG), dim3(256), 0, stream,
                       segp, pos, ib1, iw2, ib2, rb1, shw, impA, cA);
    hipLaunchKernelGGL(k_qh, dim3(64, 8), dim3(256), 0, stream, query, rw1, qhp);
    hipLaunchKernelGGL(k_ctx, dim3(BROWS), dim3(256), 0, stream,
                       query, seg, rw2, rb2, qhp, shw, impA, cA, out);
}